// Round 3
// baseline (428.992 us; speedup 1.0000x reference)
//
#include <hip/hip_runtime.h>

#define DN 64
#define DE 32
#define DO 64

// ---------------------------------------------------------------------------
// K1: per-node projections through the edge-MLP weight:
//   Ps[n] = node[n] @ W_e[0:64], Pd[n] = node[n] @ W_e[96:160]
// ---------------------------------------------------------------------------
__global__ void __launch_bounds__(256) node_pre_kernel(
    const float* __restrict__ node, const float* __restrict__ W_e,
    float* __restrict__ Ps, float* __restrict__ Pd, int n_nodes)
{
    const int lane = threadIdx.x & 63;
    const int wid  = __builtin_amdgcn_readfirstlane((int)(threadIdx.x >> 6));
    const int wpb  = blockDim.x >> 6;
    const int gw   = blockIdx.x * wpb + wid;
    const int nw   = gridDim.x * wpb;

    float Ws[64], Wd[64];
#pragma unroll
    for (int k = 0; k < 64; ++k) {
        Ws[k] = W_e[(size_t)k * DO + lane];
        Wd[k] = W_e[(size_t)(96 + k) * DO + lane];
    }

    for (int n = gw; n < n_nodes; n += nw) {
        const float* __restrict__ x = node + (size_t)n * DN;
        float as = 0.f, ad = 0.f;
#pragma unroll
        for (int k = 0; k < 64; ++k) {
            const float xk = x[k];
            as = fmaf(xk, Ws[k], as);
            ad = fmaf(xk, Wd[k], ad);
        }
        Ps[(size_t)n * DO + lane] = as;
        Pd[(size_t)n * DO + lane] = ad;
    }
}

// ---------------------------------------------------------------------------
// K2: degree histogram (int RMWs: 0.8M @ ~181 G/s measured -> ~5 us)
// ---------------------------------------------------------------------------
__global__ void __launch_bounds__(256) hist_kernel(
    const int* __restrict__ dst, int* __restrict__ cnt, int n_edges)
{
    int e = blockIdx.x * blockDim.x + threadIdx.x;
    if (e < n_edges) atomicAdd(&cnt[dst[e]], 1);
}

// ---------------------------------------------------------------------------
// K3: exclusive scan over cnt -> row_start (+ cursor copy). One block.
// Thread t owns a contiguous chunk; two-pass (sum, then write prefixes).
// ---------------------------------------------------------------------------
__global__ void __launch_bounds__(1024) scan_kernel(
    const int* __restrict__ cnt, int* __restrict__ row_start,
    int* __restrict__ cursor, int n_nodes)
{
    const int T = 1024;
    const int tid = threadIdx.x;
    const int C = (n_nodes + T - 1) / T;
    int lo = tid * C, hi = lo + C;
    if (lo > n_nodes) lo = n_nodes;
    if (hi > n_nodes) hi = n_nodes;

    int s = 0;
    for (int i = lo; i < hi; ++i) s += cnt[i];

    const int lane = tid & 63, w = tid >> 6;
    int incl = s;
#pragma unroll
    for (int off = 1; off < 64; off <<= 1) {
        int t = __shfl_up(incl, off, 64);
        if (lane >= off) incl += t;
    }
    __shared__ int wsum[16];
    if (lane == 63) wsum[w] = incl;
    __syncthreads();
    if (tid == 0) {
        int r = 0;
        for (int i = 0; i < 16; ++i) { int v = wsum[i]; wsum[i] = r; r += v; }
    }
    __syncthreads();

    int run = incl - s + wsum[w];   // exclusive prefix of this thread's chunk
    for (int i = lo; i < hi; ++i) {
        int c = cnt[i];
        row_start[i] = run;
        cursor[i]    = run;
        run += c;
    }
    if (tid == T - 1) row_start[n_nodes] = run;
}

// ---------------------------------------------------------------------------
// K4: scatter edge ids into CSR order (0.8M int RMWs)
// ---------------------------------------------------------------------------
__global__ void __launch_bounds__(256) scatter_kernel(
    const int* __restrict__ dst, int* __restrict__ cursor,
    int* __restrict__ eidx, int n_edges)
{
    int e = blockIdx.x * blockDim.x + threadIdx.x;
    if (e < n_edges) {
        int p = atomicAdd(&cursor[dst[e]], 1);
        eidx[p] = e;
    }
}

// ---------------------------------------------------------------------------
// K5: fused edge-message + per-node aggregation. Wave per node.
//   msum[n] = sum_{e in CSR(n)} relu(b_e + Pd[n] + Ps[src[e]] + edge[e]@Wm)
// Messages live only in registers -> zero f32 atomics, zero m-buffer traffic.
// eidx/src batch-prefetched lane-parallel (64 edges per load), broadcast via
// shfl + readfirstlane so er loads stay scalar (SMEM path).
// ---------------------------------------------------------------------------
__global__ void __launch_bounds__(256) agg_kernel(
    const float* __restrict__ edge, const int* __restrict__ src,
    const float* __restrict__ W_e, const float* __restrict__ b_e,
    const float* __restrict__ Ps, const float* __restrict__ Pd,
    const int* __restrict__ row_start, const int* __restrict__ eidx,
    float* __restrict__ msum, int n_nodes)
{
    const int lane = threadIdx.x & 63;
    const int wid  = threadIdx.x >> 6;
    const int n    = blockIdx.x * (blockDim.x >> 6) + wid;
    if (n >= n_nodes) return;

    float Wm[32];
#pragma unroll
    for (int k = 0; k < 32; ++k)
        Wm[k] = W_e[(size_t)(64 + k) * DO + lane];

    const float base_m = b_e[lane] + Pd[(size_t)n * DO + lane];
    const int beg = row_start[n], end = row_start[n + 1];

    float acc = 0.f;
    for (int b0 = beg; b0 < end; b0 += 64) {
        int cnt = end - b0; if (cnt > 64) cnt = 64;
        int idx = b0 + lane; if (idx >= end) idx = end - 1;
        const int mye = eidx[idx];
        const int mys = src[mye];
#pragma unroll 2
        for (int j = 0; j < cnt; ++j) {
            const int e = __builtin_amdgcn_readfirstlane(__shfl(mye, j, 64));
            const int s = __builtin_amdgcn_readfirstlane(__shfl(mys, j, 64));
            const float* __restrict__ er = edge + (size_t)e * DE;
            float m = base_m + Ps[(size_t)s * DO + lane];
#pragma unroll
            for (int k = 0; k < 32; ++k)
                m = fmaf(er[k], Wm[k], m);
            acc += fmaxf(m, 0.f);
        }
    }
    msum[(size_t)n * DO + lane] = acc;
}

// ---------------------------------------------------------------------------
// K6: node update: out = relu((msum/deg)@W_v[0:64] + node@W_v[64:128] + b_v)
// deg = row_start[n+1] - row_start[n]
// ---------------------------------------------------------------------------
__global__ void __launch_bounds__(256) node_out_kernel(
    const float* __restrict__ node, const float* __restrict__ msum,
    const int* __restrict__ row_start,
    const float* __restrict__ W_v, const float* __restrict__ b_v,
    float* __restrict__ out, int n_nodes)
{
    const int lane = threadIdx.x & 63;
    const int wid  = __builtin_amdgcn_readfirstlane((int)(threadIdx.x >> 6));
    const int wpb  = blockDim.x >> 6;
    const int gw   = blockIdx.x * wpb + wid;
    const int nw   = gridDim.x * wpb;

    float Wt[64], Wb[64];
#pragma unroll
    for (int k = 0; k < 64; ++k) {
        Wt[k] = W_v[(size_t)k * DO + lane];
        Wb[k] = W_v[(size_t)(64 + k) * DO + lane];
    }
    const float bj = b_v[lane];

    for (int n = gw; n < n_nodes; n += nw) {
        const float* __restrict__ ms = msum + (size_t)n * DO;
        const float* __restrict__ x  = node + (size_t)n * DN;
        const float dg = (float)(row_start[n + 1] - row_start[n]);
        float an = 0.f, ax = 0.f;
#pragma unroll
        for (int k = 0; k < 64; ++k) {
            an = fmaf(ms[k], Wt[k], an);
            ax = fmaf(x[k],  Wb[k], ax);
        }
        float acc = bj + ax + (dg > 0.f ? an / dg : 0.f);
        out[(size_t)n * DO + lane] = fmaxf(acc, 0.f);
    }
}

extern "C" void kernel_launch(void* const* d_in, const int* in_sizes, int n_in,
                              void* d_out, int out_size, void* d_ws, size_t ws_size,
                              hipStream_t stream)
{
    const float* node = (const float*)d_in[0];
    const float* edge = (const float*)d_in[1];
    const int*   src  = (const int*)d_in[2];
    const int*   dst  = (const int*)d_in[3];
    const float* W_e  = (const float*)d_in[4];
    const float* b_e  = (const float*)d_in[5];
    const float* W_v  = (const float*)d_in[6];
    const float* b_v  = (const float*)d_in[7];
    float* out = (float*)d_out;

    const int n_nodes = in_sizes[0] / DN;
    const int n_edges = in_sizes[2];

    // Workspace layout: Ps | Pd | msum (floats) | row_start | cnt | cursor | eidx (ints)
    float* Ps   = (float*)d_ws;
    float* Pd   = Ps   + (size_t)n_nodes * DO;
    float* msum = Pd   + (size_t)n_nodes * DO;
    int* row_start = (int*)(msum + (size_t)n_nodes * DO);
    int* cnt       = row_start + (n_nodes + 1);
    int* cursor    = cnt + n_nodes;
    int* eidx      = cursor + n_nodes;

    hipMemsetAsync(cnt, 0, (size_t)n_nodes * sizeof(int), stream);

    node_pre_kernel<<<512, 256, 0, stream>>>(node, W_e, Ps, Pd, n_nodes);
    hist_kernel<<<(n_edges + 255) / 256, 256, 0, stream>>>(dst, cnt, n_edges);
    scan_kernel<<<1, 1024, 0, stream>>>(cnt, row_start, cursor, n_nodes);
    scatter_kernel<<<(n_edges + 255) / 256, 256, 0, stream>>>(dst, cursor, eidx, n_edges);
    agg_kernel<<<(n_nodes + 3) / 4, 256, 0, stream>>>(edge, src, W_e, b_e, Ps, Pd,
                                                      row_start, eidx, msum, n_nodes);
    node_out_kernel<<<512, 256, 0, stream>>>(node, msum, row_start, W_v, b_v,
                                             out, n_nodes);
}

// Round 4
// 356.401 us; speedup vs baseline: 1.2037x; 1.2037x over previous
//
#include <hip/hip_runtime.h>

#define DN 64
#define DE 32
#define DO 64
#define NB 256   // scan phase-1 blocks (requires n_nodes <= NB*256)

// ---------------------------------------------------------------------------
// K1: per-node projections through the edge-MLP weight:
//   Ps[n] = node[n] @ W_e[0:64], Pd[n] = node[n] @ W_e[96:160]
// ---------------------------------------------------------------------------
__global__ void __launch_bounds__(256) node_pre_kernel(
    const float* __restrict__ node, const float* __restrict__ W_e,
    float* __restrict__ Ps, float* __restrict__ Pd, int n_nodes)
{
    const int lane = threadIdx.x & 63;
    const int wid  = __builtin_amdgcn_readfirstlane((int)(threadIdx.x >> 6));
    const int wpb  = blockDim.x >> 6;
    const int gw   = blockIdx.x * wpb + wid;
    const int nw   = gridDim.x * wpb;

    float Ws[64], Wd[64];
#pragma unroll
    for (int k = 0; k < 64; ++k) {
        Ws[k] = W_e[k * DO + lane];
        Wd[k] = W_e[(96 + k) * DO + lane];
    }

    for (int n = gw; n < n_nodes; n += nw) {
        const float* __restrict__ x = node + (size_t)n * DN;
        float as = 0.f, ad = 0.f;
#pragma unroll
        for (int k = 0; k < 64; ++k) {
            const float xk = x[k];
            as = fmaf(xk, Ws[k], as);
            ad = fmaf(xk, Wd[k], ad);
        }
        Ps[(size_t)n * DO + lane] = as;
        Pd[(size_t)n * DO + lane] = ad;
    }
}

// ---------------------------------------------------------------------------
// K2: degree histogram
// ---------------------------------------------------------------------------
__global__ void __launch_bounds__(256) hist_kernel(
    const int* __restrict__ dst, int* __restrict__ cnt, int n_edges)
{
    int e = blockIdx.x * blockDim.x + threadIdx.x;
    if (e < n_edges) atomicAdd(&cnt[dst[e]], 1);
}

// ---------------------------------------------------------------------------
// K3a: per-block local exclusive scan of cnt chunks + block sums.
// Block b covers [b*C, b*C+C), C = ceil(n_nodes/NB) <= 256.
// ---------------------------------------------------------------------------
__global__ void __launch_bounds__(256) scan_partial(
    const int* __restrict__ cnt, int* __restrict__ local,
    int* __restrict__ bsum, int n_nodes)
{
    const int C = (n_nodes + NB - 1) / NB;
    const int t = threadIdx.x, lane = t & 63, w = t >> 6;
    const int i = blockIdx.x * C + t;

    int v = (t < C && i < n_nodes) ? cnt[i] : 0;
    int incl = v;
#pragma unroll
    for (int off = 1; off < 64; off <<= 1) {
        int u = __shfl_up(incl, off, 64);
        if (lane >= off) incl += u;
    }
    __shared__ int ws[4], wo[4];
    if (lane == 63) ws[w] = incl;
    __syncthreads();
    if (t == 0) {
        int r = 0;
#pragma unroll
        for (int q = 0; q < 4; ++q) { wo[q] = r; r += ws[q]; }
        bsum[blockIdx.x] = r;
    }
    __syncthreads();
    if (t < C && i < n_nodes) local[i] = incl - v + wo[w];
}

// ---------------------------------------------------------------------------
// K3b: exclusive scan of the NB block sums (one block); writes total to
// row_start[n_nodes].
// ---------------------------------------------------------------------------
__global__ void __launch_bounds__(NB) scan_bsum(
    int* __restrict__ bsum, int* __restrict__ row_start, int n_nodes)
{
    const int t = threadIdx.x, lane = t & 63, w = t >> 6;
    int v = bsum[t];
    int incl = v;
#pragma unroll
    for (int off = 1; off < 64; off <<= 1) {
        int u = __shfl_up(incl, off, 64);
        if (lane >= off) incl += u;
    }
    __shared__ int ws[4], wo[4];
    if (lane == 63) ws[w] = incl;
    __syncthreads();
    if (t == 0) {
        int r = 0;
#pragma unroll
        for (int q = 0; q < 4; ++q) { wo[q] = r; r += ws[q]; }
    }
    __syncthreads();
    int excl = incl - v + wo[w];
    bsum[t] = excl;
    if (t == NB - 1) row_start[n_nodes] = excl + v;
}

// ---------------------------------------------------------------------------
// K3c: combine local prefixes + block offsets -> row_start, cursor
// ---------------------------------------------------------------------------
__global__ void __launch_bounds__(256) scan_add(
    const int* __restrict__ local, const int* __restrict__ bsum,
    int* __restrict__ row_start, int* __restrict__ cursor, int n_nodes)
{
    const int C = (n_nodes + NB - 1) / NB;
    const int i = blockIdx.x * C + threadIdx.x;
    if (threadIdx.x < C && i < n_nodes) {
        int r = local[i] + bsum[blockIdx.x];
        row_start[i] = r;
        cursor[i]    = r;
    }
}

// ---------------------------------------------------------------------------
// K4: scatter edge ids into CSR order
// ---------------------------------------------------------------------------
__global__ void __launch_bounds__(256) scatter_kernel(
    const int* __restrict__ dst, int* __restrict__ cursor,
    int* __restrict__ eidx, int n_edges)
{
    int e = blockIdx.x * blockDim.x + threadIdx.x;
    if (e < n_edges) {
        int p = atomicAdd(&cursor[dst[e]], 1);
        eidx[p] = e;
    }
}

// ---------------------------------------------------------------------------
// K5: fused edge-message + per-node aggregation. Wave per node.
// Fully wave-uniform control path: n is readfirstlane'd, so eidx[j], src[e],
// and the er row become SCALAR (s_load) accesses — no shfl broadcast, and
// scalar loads issue on the SMEM pipe, freeing VALU slots. Dot product split
// into 4 partial accumulators (dep chain 128 -> 32 cyc).
// ---------------------------------------------------------------------------
__global__ void __launch_bounds__(256) agg_kernel(
    const float* __restrict__ edge, const int* __restrict__ src,
    const float* __restrict__ W_e, const float* __restrict__ b_e,
    const float* __restrict__ Ps, const float* __restrict__ Pd,
    const int* __restrict__ row_start, const int* __restrict__ eidx,
    float* __restrict__ msum, int n_nodes)
{
    const int lane = threadIdx.x & 63;
    const int wid  = __builtin_amdgcn_readfirstlane((int)(threadIdx.x >> 6));
    const int n    = __builtin_amdgcn_readfirstlane(
                         (int)(blockIdx.x * (blockDim.x >> 6)) + wid);
    if (n >= n_nodes) return;

    float Wm[32];
#pragma unroll
    for (int k = 0; k < 32; ++k)
        Wm[k] = W_e[(64 + k) * DO + lane];

    const float base_m = b_e[lane] + Pd[(unsigned)n * DO + lane];
    const int beg = row_start[n], end = row_start[n + 1];

    float acc = 0.f;
#pragma unroll 2
    for (int j = beg; j < end; ++j) {
        const int e = eidx[j];                       // scalar (j uniform)
        const int s = src[e];                        // scalar
        const float* __restrict__ er = edge + (unsigned)e * DE;  // scalar base
        const float ps = Ps[(unsigned)s * DO + lane];            // vector gather
        float m0 = base_m + ps, m1 = 0.f, m2 = 0.f, m3 = 0.f;
#pragma unroll
        for (int k = 0; k < 32; k += 4) {
            m0 = fmaf(er[k],     Wm[k],     m0);
            m1 = fmaf(er[k + 1], Wm[k + 1], m1);
            m2 = fmaf(er[k + 2], Wm[k + 2], m2);
            m3 = fmaf(er[k + 3], Wm[k + 3], m3);
        }
        acc += fmaxf((m0 + m1) + (m2 + m3), 0.f);
    }
    msum[(unsigned)n * DO + lane] = acc;
}

// ---------------------------------------------------------------------------
// K6: node update: out = relu((msum/deg)@W_v[0:64] + node@W_v[64:128] + b_v)
// ---------------------------------------------------------------------------
__global__ void __launch_bounds__(256) node_out_kernel(
    const float* __restrict__ node, const float* __restrict__ msum,
    const int* __restrict__ row_start,
    const float* __restrict__ W_v, const float* __restrict__ b_v,
    float* __restrict__ out, int n_nodes)
{
    const int lane = threadIdx.x & 63;
    const int wid  = __builtin_amdgcn_readfirstlane((int)(threadIdx.x >> 6));
    const int wpb  = blockDim.x >> 6;
    const int gw   = blockIdx.x * wpb + wid;
    const int nw   = gridDim.x * wpb;

    float Wt[64], Wb[64];
#pragma unroll
    for (int k = 0; k < 64; ++k) {
        Wt[k] = W_v[k * DO + lane];
        Wb[k] = W_v[(64 + k) * DO + lane];
    }
    const float bj = b_v[lane];

    for (int n = gw; n < n_nodes; n += nw) {
        const float* __restrict__ ms = msum + (size_t)n * DO;
        const float* __restrict__ x  = node + (size_t)n * DN;
        const float dg = (float)(row_start[n + 1] - row_start[n]);
        float an = 0.f, ax = 0.f;
#pragma unroll
        for (int k = 0; k < 64; ++k) {
            an = fmaf(ms[k], Wt[k], an);
            ax = fmaf(x[k],  Wb[k], ax);
        }
        float acc = bj + ax + (dg > 0.f ? an / dg : 0.f);
        out[(size_t)n * DO + lane] = fmaxf(acc, 0.f);
    }
}

extern "C" void kernel_launch(void* const* d_in, const int* in_sizes, int n_in,
                              void* d_out, int out_size, void* d_ws, size_t ws_size,
                              hipStream_t stream)
{
    const float* node = (const float*)d_in[0];
    const float* edge = (const float*)d_in[1];
    const int*   src  = (const int*)d_in[2];
    const int*   dst  = (const int*)d_in[3];
    const float* W_e  = (const float*)d_in[4];
    const float* b_e  = (const float*)d_in[5];
    const float* W_v  = (const float*)d_in[6];
    const float* b_v  = (const float*)d_in[7];
    float* out = (float*)d_out;

    const int n_nodes = in_sizes[0] / DN;
    const int n_edges = in_sizes[2];

    // Workspace: Ps | Pd | msum (floats) | row_start | cnt | cursor | eidx | local | bsum
    float* Ps   = (float*)d_ws;
    float* Pd   = Ps   + (size_t)n_nodes * DO;
    float* msum = Pd   + (size_t)n_nodes * DO;
    int* row_start = (int*)(msum + (size_t)n_nodes * DO);
    int* cnt       = row_start + (n_nodes + 1);
    int* cursor    = cnt + n_nodes;
    int* eidx      = cursor + n_nodes;
    int* local     = eidx + n_edges;
    int* bsum      = local + n_nodes;

    hipMemsetAsync(cnt, 0, (size_t)n_nodes * sizeof(int), stream);

    node_pre_kernel<<<512, 256, 0, stream>>>(node, W_e, Ps, Pd, n_nodes);
    hist_kernel<<<(n_edges + 255) / 256, 256, 0, stream>>>(dst, cnt, n_edges);
    scan_partial<<<NB, 256, 0, stream>>>(cnt, local, bsum, n_nodes);
    scan_bsum<<<1, NB, 0, stream>>>(bsum, row_start, n_nodes);
    scan_add<<<NB, 256, 0, stream>>>(local, bsum, row_start, cursor, n_nodes);
    scatter_kernel<<<(n_edges + 255) / 256, 256, 0, stream>>>(dst, cursor, eidx, n_edges);
    agg_kernel<<<(n_nodes + 3) / 4, 256, 0, stream>>>(edge, src, W_e, b_e, Ps, Pd,
                                                      row_start, eidx, msum, n_nodes);
    node_out_kernel<<<512, 256, 0, stream>>>(node, msum, row_start, W_v, b_v,
                                             out, n_nodes);
}